// Round 1
// baseline (1390.738 us; speedup 1.0000x reference)
//
#include <hip/hip_runtime.h>
#include <math.h>

// Problem: B=64, N_in=1152, K_in=8, N_out=64, K_out=16, ITER=3
// u[b,o,i,k] = sum_j W[o,i,k,j] * x[b,i,j]   (recomputed on the fly, never stored)
// logits(iter t) = sum_k Vsum[b,o,k]*u[b,o,i,k] with Vsum = sum of previous v's
// c = softmax over o; s[b,o,k] = sum_i c*u ; v = squash(s)

#define TI 12         // i's per chunk
#define NCHUNK 96     // 1152 / TI
#define NBBLK 8       // 64 b / 8 per workgroup

__device__ __forceinline__ float wave_max64(float v) {
    #pragma unroll
    for (int d = 32; d >= 1; d >>= 1) v = fmaxf(v, __shfl_xor(v, d, 64));
    return v;
}
__device__ __forceinline__ float wave_sum64(float v) {
    #pragma unroll
    for (int d = 32; d >= 1; d >>= 1) v += __shfl_xor(v, d, 64);
    return v;
}

// One routing pass. UNIFORM=true -> c = 1/64 exactly (iteration 0, logits are 0).
// Grid: NCHUNK*NBBLK blocks of 256 threads (4 waves).
// wave w handles b = bblk*8 + w*2 + {0,1}; lane = o (0..63).
template<bool UNIFORM>
__global__ __launch_bounds__(256, 3)
void caps_route(const float* __restrict__ x, const float* __restrict__ W,
                const float* __restrict__ Vsum, float* __restrict__ s_out) {
    __shared__ float4 wlds[2048];          // W slice, [f4=32][o=64], XOR-swizzled
    __shared__ float4 xlds[8 * TI * 2];    // x tile, [b=8][TI][2]

    const int t = threadIdx.x;
    const int w = t >> 6;
    const int o = t & 63;
    const int chunk = blockIdx.x % NCHUNK;
    const int bblk  = blockIdx.x / NCHUNK;
    const int i0 = chunk * TI;
    const int bbase = bblk * 8 + w * 2;

    const float4* __restrict__ xg = (const float4*)x;
    const float4* __restrict__ Wg = (const float4*)W;

    // stage x tile: x[b, i0..i0+TI, 0..7] as float4 pairs
    if (t < 8 * TI * 2) {
        int b  = t / (TI * 2);
        int r  = t % (TI * 2);
        int ii = r >> 1, jh = r & 1;
        xlds[t] = xg[((bblk * 8 + b) * 1152 + i0 + ii) * 2 + jh];
    }

    // Vsum fragments for this lane's (b, o)
    float vsf[2][16];
    if (!UNIFORM) {
        const float4* vg = (const float4*)Vsum;
        #pragma unroll
        for (int bb = 0; bb < 2; ++bb) {
            #pragma unroll
            for (int q = 0; q < 4; ++q) {
                float4 v = vg[((bbase + bb) * 64 + o) * 4 + q];
                vsf[bb][q * 4 + 0] = v.x; vsf[bb][q * 4 + 1] = v.y;
                vsf[bb][q * 4 + 2] = v.z; vsf[bb][q * 4 + 3] = v.w;
            }
        }
    }

    float sacc[2][16];
    #pragma unroll
    for (int bb = 0; bb < 2; ++bb)
        #pragma unroll
        for (int k = 0; k < 16; ++k) sacc[bb][k] = 0.0f;

    for (int ii = 0; ii < TI; ++ii) {
        const int i = i0 + ii;
        __syncthreads();   // also covers x-tile staging on first pass
        // cooperative W-slice stage: 2048 float4, 8 per thread, coalesced reads
        {
            const float4* Wi = Wg + i * 32;
            #pragma unroll
            for (int r = 0; r < 8; ++r) {
                int idx = r * 256 + t;
                int oo = idx >> 5, f = idx & 31;
                float4 v = Wi[oo * 36864 + f];            // W[o,i,k,j] chunk
                wlds[f * 64 + (oo ^ (f & 7))] = v;        // swizzled write (4-way)
            }
        }
        __syncthreads();

        float4 xa[2], xb[2];
        #pragma unroll
        for (int bb = 0; bb < 2; ++bb) {
            xa[bb] = xlds[(w * 2 + bb) * (TI * 2) + ii * 2 + 0];  // broadcast
            xb[bb] = xlds[(w * 2 + bb) * (TI * 2) + ii * 2 + 1];
        }

        float u[2][16];
        float logit0 = 0.0f, logit1 = 0.0f;
        #pragma unroll
        for (int k = 0; k < 16; ++k) {
            const int f0 = 2 * k, f1 = 2 * k + 1;
            float4 w0 = wlds[f0 * 64 + (o ^ (f0 & 7))];   // conflict-free b128
            float4 w1 = wlds[f1 * 64 + (o ^ (f1 & 7))];
            float uk0 = w0.x * xa[0].x;
            uk0 = fmaf(w0.y, xa[0].y, uk0); uk0 = fmaf(w0.z, xa[0].z, uk0);
            uk0 = fmaf(w0.w, xa[0].w, uk0); uk0 = fmaf(w1.x, xb[0].x, uk0);
            uk0 = fmaf(w1.y, xb[0].y, uk0); uk0 = fmaf(w1.z, xb[0].z, uk0);
            uk0 = fmaf(w1.w, xb[0].w, uk0);
            float uk1 = w0.x * xa[1].x;
            uk1 = fmaf(w0.y, xa[1].y, uk1); uk1 = fmaf(w0.z, xa[1].z, uk1);
            uk1 = fmaf(w0.w, xa[1].w, uk1); uk1 = fmaf(w1.x, xb[1].x, uk1);
            uk1 = fmaf(w1.y, xb[1].y, uk1); uk1 = fmaf(w1.z, xb[1].z, uk1);
            uk1 = fmaf(w1.w, xb[1].w, uk1);
            u[0][k] = uk0; u[1][k] = uk1;
            if (!UNIFORM) {
                logit0 = fmaf(vsf[0][k], uk0, logit0);
                logit1 = fmaf(vsf[1][k], uk1, logit1);
            }
        }

        float c0, c1;
        if (UNIFORM) {
            c0 = c1 = (1.0f / 64.0f);
        } else {
            float m0 = wave_max64(logit0);
            float e0 = __expf(logit0 - m0);
            float c0d = wave_sum64(e0);
            c0 = e0 / c0d;
            float m1 = wave_max64(logit1);
            float e1 = __expf(logit1 - m1);
            float c1d = wave_sum64(e1);
            c1 = e1 / c1d;
        }

        #pragma unroll
        for (int k = 0; k < 16; ++k) {
            sacc[0][k] = fmaf(c0, u[0][k], sacc[0][k]);
            sacc[1][k] = fmaf(c1, u[1][k], sacc[1][k]);
        }
    }

    // accumulate partial s into global
    #pragma unroll
    for (int bb = 0; bb < 2; ++bb) {
        float* sp = s_out + ((bbase + bb) * 64 + o) * 16;
        #pragma unroll
        for (int k = 0; k < 16; ++k) atomicAdd(sp + k, sacc[bb][k]);
    }
}

// squash + Vsum update. MODE 0: Vsum=v, s=0. MODE 1: Vsum+=v, s=0. MODE 2: out=v.
template<int MODE>
__global__ __launch_bounds__(256)
void squash_k(float* __restrict__ s, float* __restrict__ Vsum, float* __restrict__ out) {
    const int t = blockIdx.x * blockDim.x + threadIdx.x;  // 0..4095 = (b,o)
    float4* sf = (float4*)s + t * 4;
    float4 q[4];
    #pragma unroll
    for (int r = 0; r < 4; ++r) q[r] = sf[r];
    float sv[16];
    #pragma unroll
    for (int r = 0; r < 4; ++r) {
        sv[r * 4 + 0] = q[r].x; sv[r * 4 + 1] = q[r].y;
        sv[r * 4 + 2] = q[r].z; sv[r * 4 + 3] = q[r].w;
    }
    float n2 = 0.0f;
    #pragma unroll
    for (int k = 0; k < 16; ++k) n2 = fmaf(sv[k], sv[k], n2);
    const float scale = n2 / (1.0f + n2) / sqrtf(n2 + 1e-7f);

    if (MODE == 0) {
        float4* vf = (float4*)Vsum + t * 4;
        #pragma unroll
        for (int r = 0; r < 4; ++r) {
            float4 v;
            v.x = scale * q[r].x; v.y = scale * q[r].y;
            v.z = scale * q[r].z; v.w = scale * q[r].w;
            vf[r] = v;
            sf[r] = make_float4(0.f, 0.f, 0.f, 0.f);
        }
    } else if (MODE == 1) {
        float4* vf = (float4*)Vsum + t * 4;
        #pragma unroll
        for (int r = 0; r < 4; ++r) {
            float4 v = vf[r];
            v.x = fmaf(scale, q[r].x, v.x); v.y = fmaf(scale, q[r].y, v.y);
            v.z = fmaf(scale, q[r].z, v.z); v.w = fmaf(scale, q[r].w, v.w);
            vf[r] = v;
            sf[r] = make_float4(0.f, 0.f, 0.f, 0.f);
        }
    } else {
        float4* of = (float4*)out + t * 4;
        #pragma unroll
        for (int r = 0; r < 4; ++r) {
            float4 v;
            v.x = scale * q[r].x; v.y = scale * q[r].y;
            v.z = scale * q[r].z; v.w = scale * q[r].w;
            of[r] = v;
        }
    }
}

extern "C" void kernel_launch(void* const* d_in, const int* in_sizes, int n_in,
                              void* d_out, int out_size, void* d_ws, size_t ws_size,
                              hipStream_t stream) {
    const float* x = (const float*)d_in[0];   // [64,1152,8]
    const float* W = (const float*)d_in[1];   // [64,1152,16,8]
    float* out = (float*)d_out;               // [64,64,16]
    float* s   = (float*)d_ws;                // 65536 floats
    float* Vs  = s + 65536;                   // 65536 floats

    hipMemsetAsync(s, 0, 65536 * sizeof(float), stream);

    dim3 grid(NCHUNK * NBBLK), blk(256);
    dim3 sg(16), sb(256);

    // iteration 0 (uniform c)
    caps_route<true ><<<grid, blk, 0, stream>>>(x, W, nullptr, s);
    squash_k<0><<<sg, sb, 0, stream>>>(s, Vs, out);
    // iteration 1
    caps_route<false><<<grid, blk, 0, stream>>>(x, W, Vs, s);
    squash_k<1><<<sg, sb, 0, stream>>>(s, Vs, out);
    // iteration 2
    caps_route<false><<<grid, blk, 0, stream>>>(x, W, Vs, s);
    squash_k<2><<<sg, sb, 0, stream>>>(s, Vs, out);
}

// Round 2
// 315.524 us; speedup vs baseline: 4.4077x; 4.4077x over previous
//
#include <hip/hip_runtime.h>
#include <math.h>

// B=64, N_in=1152, K_in=8, N_out=64, K_out=16, ITER=3
// u recomputed on the fly; logits via running Vsum; no global atomics.

#define TI 12         // i's per chunk
#define NCHUNK 96     // 1152 / TI
#define NBBLK 8       // 8 b-groups of 8

__device__ __forceinline__ float wave_max64(float v) {
    #pragma unroll
    for (int d = 32; d >= 1; d >>= 1) v = fmaxf(v, __shfl_xor(v, d, 64));
    return v;
}
__device__ __forceinline__ float wave_sum64(float v) {
    #pragma unroll
    for (int d = 32; d >= 1; d >>= 1) v += __shfl_xor(v, d, 64);
    return v;
}

// One routing pass. UNIFORM: c = 1/64 (iteration 0). DIRECT: write per-chunk
// partials (no atomics); else atomicAdd into dense s (fallback).
// Grid: NCHUNK*NBBLK blocks of 256 threads; wave w owns b = bblk*8+w*2+{0,1}; lane = o.
template<bool UNIFORM, bool DIRECT>
__global__ __launch_bounds__(256, 3)
void caps_route(const float* __restrict__ x, const float* __restrict__ W,
                const float* __restrict__ Vsum, float* __restrict__ s_out) {
    __shared__ float4 wlds[2048];          // W slice [f4=32][o=64], XOR-swizzled
    __shared__ float4 xlds[8 * TI * 2];    // x tile [b=8][TI][2]

    const int t = threadIdx.x;
    const int w = t >> 6;
    const int o = t & 63;
    const int chunk = blockIdx.x % NCHUNK;
    const int bblk  = blockIdx.x / NCHUNK;
    const int i0 = chunk * TI;
    const int bbase = bblk * 8 + w * 2;

    const float4* __restrict__ xg = (const float4*)x;
    const float4* __restrict__ Wg = (const float4*)W;

    // stage x tile
    if (t < 8 * TI * 2) {
        int b  = t / (TI * 2);
        int r  = t % (TI * 2);
        int ii = r >> 1, jh = r & 1;
        xlds[t] = xg[((bblk * 8 + b) * 1152 + i0 + ii) * 2 + jh];
    }

    float vsf[2][16];
    if (!UNIFORM) {
        const float4* vg = (const float4*)Vsum;
        #pragma unroll
        for (int bb = 0; bb < 2; ++bb) {
            #pragma unroll
            for (int q = 0; q < 4; ++q) {
                float4 v = vg[((bbase + bb) * 64 + o) * 4 + q];
                vsf[bb][q * 4 + 0] = v.x; vsf[bb][q * 4 + 1] = v.y;
                vsf[bb][q * 4 + 2] = v.z; vsf[bb][q * 4 + 3] = v.w;
            }
        }
    }

    // prefetch W slice for ii=0 into registers
    float4 wr[8];
    {
        const float4* Wi = Wg + (size_t)i0 * 32;
        #pragma unroll
        for (int r = 0; r < 8; ++r) {
            int idx = r * 256 + t;
            wr[r] = Wi[(size_t)(idx >> 5) * 36864 + (idx & 31)];
        }
    }

    float sacc[2][16];
    #pragma unroll
    for (int bb = 0; bb < 2; ++bb)
        #pragma unroll
        for (int k = 0; k < 16; ++k) sacc[bb][k] = 0.0f;

    for (int ii = 0; ii < TI; ++ii) {
        __syncthreads();   // prior reads of wlds done (and x stage visible)
        #pragma unroll
        for (int r = 0; r < 8; ++r) {
            int idx = r * 256 + t;
            int oo = idx >> 5, f = idx & 31;
            wlds[f * 64 + (oo ^ (f & 7))] = wr[r];
        }
        __syncthreads();

        if (ii + 1 < TI) {   // issue next slice's loads; latency hides under compute
            const float4* Wi = Wg + (size_t)(i0 + ii + 1) * 32;
            #pragma unroll
            for (int r = 0; r < 8; ++r) {
                int idx = r * 256 + t;
                wr[r] = Wi[(size_t)(idx >> 5) * 36864 + (idx & 31)];
            }
        }

        float4 xa[2], xb[2];
        #pragma unroll
        for (int bb = 0; bb < 2; ++bb) {
            xa[bb] = xlds[(w * 2 + bb) * (TI * 2) + ii * 2 + 0];
            xb[bb] = xlds[(w * 2 + bb) * (TI * 2) + ii * 2 + 1];
        }

        float u[2][16];
        float logit0 = 0.0f, logit1 = 0.0f;
        #pragma unroll
        for (int k = 0; k < 16; ++k) {
            const int f0 = 2 * k, f1 = 2 * k + 1;
            float4 w0 = wlds[f0 * 64 + (o ^ (f0 & 7))];
            float4 w1 = wlds[f1 * 64 + (o ^ (f1 & 7))];
            float uk0 = w0.x * xa[0].x;
            uk0 = fmaf(w0.y, xa[0].y, uk0); uk0 = fmaf(w0.z, xa[0].z, uk0);
            uk0 = fmaf(w0.w, xa[0].w, uk0); uk0 = fmaf(w1.x, xb[0].x, uk0);
            uk0 = fmaf(w1.y, xb[0].y, uk0); uk0 = fmaf(w1.z, xb[0].z, uk0);
            uk0 = fmaf(w1.w, xb[0].w, uk0);
            float uk1 = w0.x * xa[1].x;
            uk1 = fmaf(w0.y, xa[1].y, uk1); uk1 = fmaf(w0.z, xa[1].z, uk1);
            uk1 = fmaf(w0.w, xa[1].w, uk1); uk1 = fmaf(w1.x, xb[1].x, uk1);
            uk1 = fmaf(w1.y, xb[1].y, uk1); uk1 = fmaf(w1.z, xb[1].z, uk1);
            uk1 = fmaf(w1.w, xb[1].w, uk1);
            u[0][k] = uk0; u[1][k] = uk1;
            if (!UNIFORM) {
                logit0 = fmaf(vsf[0][k], uk0, logit0);
                logit1 = fmaf(vsf[1][k], uk1, logit1);
            }
        }

        float c0, c1;
        if (UNIFORM) {
            c0 = c1 = (1.0f / 64.0f);
        } else {
            float m0 = wave_max64(logit0);
            float e0 = __expf(logit0 - m0);
            c0 = e0 / wave_sum64(e0);
            float m1 = wave_max64(logit1);
            float e1 = __expf(logit1 - m1);
            c1 = e1 / wave_sum64(e1);
        }

        #pragma unroll
        for (int k = 0; k < 16; ++k) {
            sacc[0][k] = fmaf(c0, u[0][k], sacc[0][k]);
            sacc[1][k] = fmaf(c1, u[1][k], sacc[1][k]);
        }
    }

    if (DIRECT) {
        // plain coalesced stores to private chunk slot: [chunk][b][o][k]
        #pragma unroll
        for (int bb = 0; bb < 2; ++bb) {
            float4* sp = (float4*)s_out + (((size_t)chunk * 64 + (bbase + bb)) * 64 + o) * 4;
            sp[0] = make_float4(sacc[bb][0], sacc[bb][1], sacc[bb][2], sacc[bb][3]);
            sp[1] = make_float4(sacc[bb][4], sacc[bb][5], sacc[bb][6], sacc[bb][7]);
            sp[2] = make_float4(sacc[bb][8], sacc[bb][9], sacc[bb][10], sacc[bb][11]);
            sp[3] = make_float4(sacc[bb][12], sacc[bb][13], sacc[bb][14], sacc[bb][15]);
        }
    } else {
        #pragma unroll
        for (int bb = 0; bb < 2; ++bb) {
            float* sp = s_out + ((bbase + bb) * 64 + o) * 16;
            #pragma unroll
            for (int k = 0; k < 16; ++k) atomicAdd(sp + k, sacc[bb][k]);
        }
    }
}

// Reduce 96 chunk-partials per (b,o), then squash.
// MODE 0: Vsum=v; 1: Vsum+=v; 2: out=v.
// Grid: 256 blocks x 256 thr. Block handles 16 (b,o) pairs; thread = (pair p, chunk-group q of 6).
template<int MODE>
__global__ __launch_bounds__(256)
void reduce_squash(const float* __restrict__ sp, float* __restrict__ Vs, float* __restrict__ out) {
    const int t = threadIdx.x;
    const int p = t >> 4;          // pair 0..15
    const int q = t & 15;          // chunk group 0..15 (6 chunks each)
    const int pair = blockIdx.x * 16 + p;
    const int b = pair >> 6, o = pair & 63;

    float acc[16];
    #pragma unroll
    for (int k = 0; k < 16; ++k) acc[k] = 0.0f;

    const float4* base = (const float4*)sp;
    for (int c = q * 6; c < q * 6 + 6; ++c) {
        const float4* pptr = base + (((size_t)c * 64 + b) * 64 + o) * 4;
        float4 v0 = pptr[0], v1 = pptr[1], v2 = pptr[2], v3 = pptr[3];
        acc[0] += v0.x; acc[1] += v0.y; acc[2]  += v0.z; acc[3]  += v0.w;
        acc[4] += v1.x; acc[5] += v1.y; acc[6]  += v1.z; acc[7]  += v1.w;
        acc[8] += v2.x; acc[9] += v2.y; acc[10] += v2.z; acc[11] += v2.w;
        acc[12] += v3.x; acc[13] += v3.y; acc[14] += v3.z; acc[15] += v3.w;
    }

    // butterfly over the 16 q-lanes (lanes p*16..p*16+15 within the wave)
    #pragma unroll
    for (int d = 1; d < 16; d <<= 1) {
        #pragma unroll
        for (int k = 0; k < 16; ++k) acc[k] += __shfl_xor(acc[k], d, 64);
    }

    if (q == 0) {
        float n2 = 0.0f;
        #pragma unroll
        for (int k = 0; k < 16; ++k) n2 = fmaf(acc[k], acc[k], n2);
        const float scale = n2 / (1.0f + n2) / sqrtf(n2 + 1e-7f);

        if (MODE == 0) {
            float4* vf = (float4*)Vs + (size_t)pair * 4;
            #pragma unroll
            for (int r = 0; r < 4; ++r)
                vf[r] = make_float4(scale * acc[r*4+0], scale * acc[r*4+1],
                                    scale * acc[r*4+2], scale * acc[r*4+3]);
        } else if (MODE == 1) {
            float4* vf = (float4*)Vs + (size_t)pair * 4;
            #pragma unroll
            for (int r = 0; r < 4; ++r) {
                float4 v = vf[r];
                v.x = fmaf(scale, acc[r*4+0], v.x); v.y = fmaf(scale, acc[r*4+1], v.y);
                v.z = fmaf(scale, acc[r*4+2], v.z); v.w = fmaf(scale, acc[r*4+3], v.w);
                vf[r] = v;
            }
        } else {
            float4* of = (float4*)out + (size_t)pair * 4;
            #pragma unroll
            for (int r = 0; r < 4; ++r)
                of[r] = make_float4(scale * acc[r*4+0], scale * acc[r*4+1],
                                    scale * acc[r*4+2], scale * acc[r*4+3]);
        }
    }
}

// Fallback squash for the atomic path. MODE 0: Vsum=v,s=0; 1: Vsum+=v,s=0; 2: out=v.
template<int MODE>
__global__ __launch_bounds__(256)
void squash_k(float* __restrict__ s, float* __restrict__ Vsum, float* __restrict__ out) {
    const int t = blockIdx.x * blockDim.x + threadIdx.x;
    float4* sf = (float4*)s + t * 4;
    float4 qv[4];
    #pragma unroll
    for (int r = 0; r < 4; ++r) qv[r] = sf[r];
    float n2 = 0.0f;
    #pragma unroll
    for (int r = 0; r < 4; ++r)
        n2 = fmaf(qv[r].x, qv[r].x, fmaf(qv[r].y, qv[r].y, fmaf(qv[r].z, qv[r].z, fmaf(qv[r].w, qv[r].w, n2))));
    const float scale = n2 / (1.0f + n2) / sqrtf(n2 + 1e-7f);

    if (MODE == 0 || MODE == 1) {
        float4* vf = (float4*)Vsum + t * 4;
        #pragma unroll
        for (int r = 0; r < 4; ++r) {
            float4 v = (MODE == 1) ? vf[r] : make_float4(0.f, 0.f, 0.f, 0.f);
            v.x = fmaf(scale, qv[r].x, v.x); v.y = fmaf(scale, qv[r].y, v.y);
            v.z = fmaf(scale, qv[r].z, v.z); v.w = fmaf(scale, qv[r].w, v.w);
            vf[r] = v;
            sf[r] = make_float4(0.f, 0.f, 0.f, 0.f);
        }
    } else {
        float4* of = (float4*)out + t * 4;
        #pragma unroll
        for (int r = 0; r < 4; ++r)
            of[r] = make_float4(scale * qv[r].x, scale * qv[r].y, scale * qv[r].z, scale * qv[r].w);
    }
}

extern "C" void kernel_launch(void* const* d_in, const int* in_sizes, int n_in,
                              void* d_out, int out_size, void* d_ws, size_t ws_size,
                              hipStream_t stream) {
    const float* x = (const float*)d_in[0];   // [64,1152,8]
    const float* W = (const float*)d_in[1];   // [64,1152,16,8]
    float* out = (float*)d_out;               // [64,64,16]

    float* Vs = (float*)d_ws;                                  // 65536 floats
    float* sp = Vs + 65536;                                    // partials
    const size_t need = (65536ull + (size_t)NCHUNK * 64 * 64 * 16) * 4;

    dim3 grid(NCHUNK * NBBLK), blk(256);

    if (ws_size >= need) {
        dim3 rg(256), rb(256);
        caps_route<true , true ><<<grid, blk, 0, stream>>>(x, W, nullptr, sp);
        reduce_squash<0><<<rg, rb, 0, stream>>>(sp, Vs, out);
        caps_route<false, true ><<<grid, blk, 0, stream>>>(x, W, Vs, sp);
        reduce_squash<1><<<rg, rb, 0, stream>>>(sp, Vs, out);
        caps_route<false, true ><<<grid, blk, 0, stream>>>(x, W, Vs, sp);
        reduce_squash<2><<<rg, rb, 0, stream>>>(sp, Vs, out);
    } else {
        // atomic fallback (round-1 behavior): s = sp area start (256 KB)
        float* s = sp;
        hipMemsetAsync(s, 0, 65536 * sizeof(float), stream);
        dim3 sg(16), sb(256);
        caps_route<true , false><<<grid, blk, 0, stream>>>(x, W, nullptr, s);
        squash_k<0><<<sg, sb, 0, stream>>>(s, Vs, out);
        caps_route<false, false><<<grid, blk, 0, stream>>>(x, W, Vs, s);
        squash_k<1><<<sg, sb, 0, stream>>>(s, Vs, out);
        caps_route<false, false><<<grid, blk, 0, stream>>>(x, W, Vs, s);
        squash_k<2><<<sg, sb, 0, stream>>>(s, Vs, out);
    }
}

// Round 3
// 170.672 us; speedup vs baseline: 8.1486x; 1.8487x over previous
//
#include <hip/hip_runtime.h>
#include <math.h>

// B=64, N_in=1152, K_in=8, N_out=64, K_out=16, ITER=3
// u recomputed on the fly; logits via running Vsum; no atomics; no spills.

#define TI 18         // i's per chunk
#define NCHUNK 64     // 1152 / TI
#define NBBLK 8       // 8 b per block (1 per wave)

__device__ __forceinline__ float wave_max64(float v) {
    #pragma unroll
    for (int d = 32; d >= 1; d >>= 1) v = fmaxf(v, __shfl_xor(v, d, 64));
    return v;
}
__device__ __forceinline__ float wave_sum64(float v) {
    #pragma unroll
    for (int d = 32; d >= 1; d >>= 1) v += __shfl_xor(v, d, 64);
    return v;
}

// Grid: NBBLK*NCHUNK = 512 blocks x 512 threads (8 waves).
// wave w owns b = bblk*8 + w; lane = o. Double-buffered W slice in LDS.
template<bool UNIFORM, bool DIRECT>
__global__ __launch_bounds__(512, 4)
void caps_route(const float* __restrict__ x, const float* __restrict__ W,
                const float* __restrict__ Vsum, float* __restrict__ s_out) {
    __shared__ float4 wlds[2][2048];          // [buf][f=32][o=64], XOR-swizzled
    __shared__ float4 xlds[NBBLK * TI * 2];   // x tile [b=8][TI][2]

    const int t = threadIdx.x;
    const int w = t >> 6;          // wave = local b
    const int o = t & 63;
    const int chunk = blockIdx.x % NCHUNK;
    const int bblk  = blockIdx.x / NCHUNK;
    const int i0 = chunk * TI;
    const int b  = bblk * 8 + w;

    const float4* __restrict__ xg = (const float4*)x;
    const float4* __restrict__ Wg = (const float4*)W;

    // stage x tile for the whole chunk (visible after first barrier)
    if (t < NBBLK * TI * 2) {
        int bb = t / (TI * 2), r = t % (TI * 2);
        xlds[t] = xg[((bblk * 8 + bb) * 1152 + i0 + (r >> 1)) * 2 + (r & 1)];
    }

    float vsf[16];
    if (!UNIFORM) {
        const float4* vg = (const float4*)Vsum;
        #pragma unroll
        for (int q = 0; q < 4; ++q) {
            float4 v = vg[((size_t)b * 64 + o) * 4 + q];
            vsf[q*4+0] = v.x; vsf[q*4+1] = v.y; vsf[q*4+2] = v.z; vsf[q*4+3] = v.w;
        }
    }

    float sacc[16];
    #pragma unroll
    for (int k = 0; k < 16; ++k) sacc[k] = 0.0f;

    // prologue: stage slice 0 into buf 0 (4 float4/thread)
    float4 wr[4];
    {
        const float4* Wi = Wg + (size_t)i0 * 32;
        #pragma unroll
        for (int r = 0; r < 4; ++r) {
            int idx = r * 512 + t;
            wr[r] = Wi[(size_t)(idx >> 5) * 36864 + (idx & 31)];
        }
        #pragma unroll
        for (int r = 0; r < 4; ++r) {
            int idx = r * 512 + t;
            wlds[0][(idx & 31) * 64 + ((idx >> 5) ^ (idx & 7))] = wr[r];
        }
    }

    for (int ii = 0; ii < TI; ++ii) {
        const int cur = ii & 1;
        __syncthreads();   // buf[cur] writes from prev iter (or prologue) visible

        // T14: issue next slice's global loads before compute
        if (ii + 1 < TI) {
            const float4* Wi = Wg + (size_t)(i0 + ii + 1) * 32;
            #pragma unroll
            for (int r = 0; r < 4; ++r) {
                int idx = r * 512 + t;
                wr[r] = Wi[(size_t)(idx >> 5) * 36864 + (idx & 31)];
            }
        }

        float4 xa = xlds[w * (TI * 2) + ii * 2 + 0];   // wave-uniform broadcast
        float4 xb = xlds[w * (TI * 2) + ii * 2 + 1];

        const float4* wb = wlds[cur];
        float u[16];
        float logit = 0.0f;
        #pragma unroll
        for (int k = 0; k < 16; ++k) {
            const int f0 = 2 * k, f1 = 2 * k + 1;
            float4 w0 = wb[f0 * 64 + (o ^ (f0 & 7))];   // stride-16B, conflict-free
            float4 w1 = wb[f1 * 64 + (o ^ (f1 & 7))];
            float uk = w0.x * xa.x;
            uk = fmaf(w0.y, xa.y, uk); uk = fmaf(w0.z, xa.z, uk); uk = fmaf(w0.w, xa.w, uk);
            uk = fmaf(w1.x, xb.x, uk); uk = fmaf(w1.y, xb.y, uk); uk = fmaf(w1.z, xb.z, uk);
            uk = fmaf(w1.w, xb.w, uk);
            u[k] = uk;
            if (!UNIFORM) logit = fmaf(vsf[k], uk, logit);
        }

        float c;
        if (UNIFORM) {
            c = 1.0f / 64.0f;
        } else {
            float m = wave_max64(logit);
            float e = __expf(logit - m);
            c = e / wave_sum64(e);
        }

        #pragma unroll
        for (int k = 0; k < 16; ++k) sacc[k] = fmaf(c, u[k], sacc[k]);

        // write next slice into the other buffer (no extra barrier needed)
        if (ii + 1 < TI) {
            #pragma unroll
            for (int r = 0; r < 4; ++r) {
                int idx = r * 512 + t;
                wlds[cur ^ 1][(idx & 31) * 64 + ((idx >> 5) ^ (idx & 7))] = wr[r];
            }
        }
    }

    if (DIRECT) {
        // private chunk slot [chunk][b][o][k], plain coalesced stores
        float4* sp = (float4*)s_out + (((size_t)chunk * 64 + b) * 64 + o) * 4;
        sp[0] = make_float4(sacc[0],  sacc[1],  sacc[2],  sacc[3]);
        sp[1] = make_float4(sacc[4],  sacc[5],  sacc[6],  sacc[7]);
        sp[2] = make_float4(sacc[8],  sacc[9],  sacc[10], sacc[11]);
        sp[3] = make_float4(sacc[12], sacc[13], sacc[14], sacc[15]);
    } else {
        float* sp = s_out + ((size_t)b * 64 + o) * 16;
        #pragma unroll
        for (int k = 0; k < 16; ++k) atomicAdd(sp + k, sacc[k]);
    }
}

// Reduce NCHUNK chunk-partials per (b,o), then squash.
// MODE 0: Vsum=v; 1: Vsum+=v; 2: out=v.
// Grid: 256 blocks x 256 thr; block = 16 (b,o) pairs; thread = (pair p, chunk-group q).
template<int MODE>
__global__ __launch_bounds__(256)
void reduce_squash(const float* __restrict__ sp, float* __restrict__ Vs, float* __restrict__ out) {
    const int t = threadIdx.x;
    const int p = t >> 4;          // pair 0..15
    const int q = t & 15;          // chunk group 0..15 (NCHUNK/16 chunks each)
    const int pair = blockIdx.x * 16 + p;
    const int b = pair >> 6, o = pair & 63;

    float acc[16];
    #pragma unroll
    for (int k = 0; k < 16; ++k) acc[k] = 0.0f;

    const float4* base = (const float4*)sp;
    for (int c = q * (NCHUNK/16); c < (q + 1) * (NCHUNK/16); ++c) {
        const float4* pptr = base + (((size_t)c * 64 + b) * 64 + o) * 4;
        float4 v0 = pptr[0], v1 = pptr[1], v2 = pptr[2], v3 = pptr[3];
        acc[0] += v0.x; acc[1] += v0.y; acc[2]  += v0.z; acc[3]  += v0.w;
        acc[4] += v1.x; acc[5] += v1.y; acc[6]  += v1.z; acc[7]  += v1.w;
        acc[8] += v2.x; acc[9] += v2.y; acc[10] += v2.z; acc[11] += v2.w;
        acc[12] += v3.x; acc[13] += v3.y; acc[14] += v3.z; acc[15] += v3.w;
    }

    #pragma unroll
    for (int d = 1; d < 16; d <<= 1) {
        #pragma unroll
        for (int k = 0; k < 16; ++k) acc[k] += __shfl_xor(acc[k], d, 64);
    }

    if (q == 0) {
        float n2 = 0.0f;
        #pragma unroll
        for (int k = 0; k < 16; ++k) n2 = fmaf(acc[k], acc[k], n2);
        const float scale = n2 / (1.0f + n2) / sqrtf(n2 + 1e-7f);

        if (MODE == 0) {
            float4* vf = (float4*)Vs + (size_t)pair * 4;
            #pragma unroll
            for (int r = 0; r < 4; ++r)
                vf[r] = make_float4(scale * acc[r*4+0], scale * acc[r*4+1],
                                    scale * acc[r*4+2], scale * acc[r*4+3]);
        } else if (MODE == 1) {
            float4* vf = (float4*)Vs + (size_t)pair * 4;
            #pragma unroll
            for (int r = 0; r < 4; ++r) {
                float4 v = vf[r];
                v.x = fmaf(scale, acc[r*4+0], v.x); v.y = fmaf(scale, acc[r*4+1], v.y);
                v.z = fmaf(scale, acc[r*4+2], v.z); v.w = fmaf(scale, acc[r*4+3], v.w);
                vf[r] = v;
            }
        } else {
            float4* of = (float4*)out + (size_t)pair * 4;
            #pragma unroll
            for (int r = 0; r < 4; ++r)
                of[r] = make_float4(scale * acc[r*4+0], scale * acc[r*4+1],
                                    scale * acc[r*4+2], scale * acc[r*4+3]);
        }
    }
}

// Fallback squash for the atomic path. MODE 0: Vsum=v,s=0; 1: Vsum+=v,s=0; 2: out=v.
template<int MODE>
__global__ __launch_bounds__(256)
void squash_k(float* __restrict__ s, float* __restrict__ Vsum, float* __restrict__ out) {
    const int t = blockIdx.x * blockDim.x + threadIdx.x;
    float4* sf = (float4*)s + t * 4;
    float4 qv[4];
    #pragma unroll
    for (int r = 0; r < 4; ++r) qv[r] = sf[r];
    float n2 = 0.0f;
    #pragma unroll
    for (int r = 0; r < 4; ++r)
        n2 = fmaf(qv[r].x, qv[r].x, fmaf(qv[r].y, qv[r].y, fmaf(qv[r].z, qv[r].z, fmaf(qv[r].w, qv[r].w, n2))));
    const float scale = n2 / (1.0f + n2) / sqrtf(n2 + 1e-7f);

    if (MODE == 0 || MODE == 1) {
        float4* vf = (float4*)Vsum + t * 4;
        #pragma unroll
        for (int r = 0; r < 4; ++r) {
            float4 v = (MODE == 1) ? vf[r] : make_float4(0.f, 0.f, 0.f, 0.f);
            v.x = fmaf(scale, qv[r].x, v.x); v.y = fmaf(scale, qv[r].y, v.y);
            v.z = fmaf(scale, qv[r].z, v.z); v.w = fmaf(scale, qv[r].w, v.w);
            vf[r] = v;
            sf[r] = make_float4(0.f, 0.f, 0.f, 0.f);
        }
    } else {
        float4* of = (float4*)out + t * 4;
        #pragma unroll
        for (int r = 0; r < 4; ++r)
            of[r] = make_float4(scale * qv[r].x, scale * qv[r].y, scale * qv[r].z, scale * qv[r].w);
    }
}

extern "C" void kernel_launch(void* const* d_in, const int* in_sizes, int n_in,
                              void* d_out, int out_size, void* d_ws, size_t ws_size,
                              hipStream_t stream) {
    const float* x = (const float*)d_in[0];   // [64,1152,8]
    const float* W = (const float*)d_in[1];   // [64,1152,16,8]
    float* out = (float*)d_out;               // [64,64,16]

    float* Vs = (float*)d_ws;                                  // 65536 floats
    float* sp = Vs + 65536;                                    // partials
    const size_t need = (65536ull + (size_t)NCHUNK * 64 * 64 * 16) * 4;

    dim3 grid(NBBLK * NCHUNK), blk(512);

    if (ws_size >= need) {
        dim3 rg(256), rb(256);
        caps_route<true , true ><<<grid, blk, 0, stream>>>(x, W, nullptr, sp);
        reduce_squash<0><<<rg, rb, 0, stream>>>(sp, Vs, out);
        caps_route<false, true ><<<grid, blk, 0, stream>>>(x, W, Vs, sp);
        reduce_squash<1><<<rg, rb, 0, stream>>>(sp, Vs, out);
        caps_route<false, true ><<<grid, blk, 0, stream>>>(x, W, Vs, sp);
        reduce_squash<2><<<rg, rb, 0, stream>>>(sp, Vs, out);
    } else {
        // atomic fallback: dense s at sp (256 KB)
        float* s = sp;
        hipMemsetAsync(s, 0, 65536 * sizeof(float), stream);
        dim3 sg(16), sb(256);
        caps_route<true , false><<<grid, blk, 0, stream>>>(x, W, nullptr, s);
        squash_k<0><<<sg, sb, 0, stream>>>(s, Vs, out);
        caps_route<false, false><<<grid, blk, 0, stream>>>(x, W, Vs, s);
        squash_k<1><<<sg, sb, 0, stream>>>(s, Vs, out);
        caps_route<false, false><<<grid, blk, 0, stream>>>(x, W, Vs, s);
        squash_k<2><<<sg, sb, 0, stream>>>(s, Vs, out);
    }
}